// Round 4
// baseline (752.881 us; speedup 1.0000x reference)
//
#include <hip/hip_runtime.h>
#include <hip/hip_bf16.h>
#include <cstdint>

#define N_NODES 100000
#define N_EDGES 1600000
#define F_IN 256
#define F_HID 128
#define F_OUT 64
#define NEG_SLOPE 0.2f

// bucketed CSR build
#define BSH 7                      // 128 nodes per bucket
#define NB 782                     // ceil(100000/128)
#define CAP 3072                   // csr slots per bucket (edges+selfloops), mean 2304
#define CAPS 3072                  // staged pair slots per bucket (edges only), mean 2176

typedef __attribute__((ext_vector_type(8))) short bf16x8;
typedef __attribute__((ext_vector_type(4))) float f32x4;

__device__ __forceinline__ ushort f2bf(float f) {
  uint u = __float_as_uint(f);
  u += 0x7fffu + ((u >> 16) & 1u);   // RNE
  return (ushort)(u >> 16);
}
__device__ __forceinline__ float bf2f(ushort s) {
  return __uint_as_float(((uint)s) << 16);
}
__device__ __forceinline__ uint pack2(float a, float b) {
  return (uint)f2bf(a) | ((uint)f2bf(b) << 16);
}

// ------------------------------------------------- W prep: transpose + bf16
__global__ void wprep_kernel(const float* __restrict__ W, ushort* __restrict__ Wt,
                             int K, int Ncol) {
  int i = blockIdx.x * blockDim.x + threadIdx.x;
  if (i < K * Ncol) {
    int k = i / Ncol, c = i % Ncol;
    Wt[(size_t)c * K + k] = f2bf(W[i]);
  }
}

// ----------------------------------------------------------- MFMA GEMM ----
// C[M x BN] (bf16) = A[M x K] @ Bt^T, Bt is [BN][K] bf16. Block: 256 thr,
// BM=128, 4 waves each own 32 rows x BN cols. K-step 32, 16x16x32 mfma.
// Fused epilogue: as_[r] = h[r,:].a_src, ad_[r] = h[r,:].a_dst (f32 acc).
template <int BN, int K, bool AF32>
__global__ __launch_bounds__(256) void gemm_mfma(
    const void* __restrict__ Ap, const ushort* __restrict__ Bt,
    ushort* __restrict__ Cb, const float* __restrict__ a_src,
    const float* __restrict__ a_dst, float* __restrict__ as_,
    float* __restrict__ ad_, int M) {
  constexpr int CT = BN / 16;
  __shared__ __align__(16) ushort Alds[128 * 32];
  __shared__ __align__(16) ushort Blds[BN * 32];
  const int tid = threadIdx.x;
  const int wave = tid >> 6, lane = tid & 63;
  const int lr = lane & 15, lq = lane >> 4;
  const int gm0 = blockIdx.x * 128;

  f32x4 acc[2][CT];
#pragma unroll
  for (int a = 0; a < 2; ++a)
#pragma unroll
    for (int b = 0; b < CT; ++b)
#pragma unroll
      for (int e = 0; e < 4; ++e) acc[a][b][e] = 0.f;

  for (int kt = 0; kt < K; kt += 32) {
    // A stage: 512 segs of 16B (8 bf16), seg-XOR swizzled
#pragma unroll
    for (int i = 0; i < 2; ++i) {
      int sid = i * 256 + tid;
      int row = sid >> 2, q = sid & 3;
      int gm = gm0 + row;
      uint4 w = make_uint4(0u, 0u, 0u, 0u);
      if (gm < M) {
        if (AF32) {
          const float* s = (const float*)Ap + (size_t)gm * K + kt + q * 8;
          float4 u = *(const float4*)s;
          float4 v = *(const float4*)(s + 4);
          w.x = pack2(u.x, u.y); w.y = pack2(u.z, u.w);
          w.z = pack2(v.x, v.y); w.w = pack2(v.z, v.w);
        } else {
          w = *(const uint4*)((const ushort*)Ap + (size_t)gm * K + kt + q * 8);
        }
      }
      int phys = row * 4 + (q ^ ((row >> 2) & 3));
      *(uint4*)&Alds[phys * 8] = w;
    }
    // B stage
#pragma unroll
    for (int i = 0; i < BN * 4 / 256; ++i) {
      int sid = i * 256 + tid;
      int row = sid >> 2, q = sid & 3;
      uint4 w = *(const uint4*)(Bt + (size_t)row * K + kt + q * 8);
      int phys = row * 4 + (q ^ ((row >> 2) & 3));
      *(uint4*)&Blds[phys * 8] = w;
    }
    __syncthreads();

    bf16x8 af[2], bfr[CT];
#pragma unroll
    for (int rt = 0; rt < 2; ++rt) {
      int r = wave * 32 + rt * 16 + lr;
      af[rt] = *(const bf16x8*)&Alds[(r * 4 + (lq ^ ((r >> 2) & 3))) * 8];
    }
#pragma unroll
    for (int c = 0; c < CT; ++c) {
      int r = c * 16 + lr;
      bfr[c] = *(const bf16x8*)&Blds[(r * 4 + (lq ^ ((r >> 2) & 3))) * 8];
    }
#pragma unroll
    for (int rt = 0; rt < 2; ++rt)
#pragma unroll
      for (int c = 0; c < CT; ++c)
        acc[rt][c] = __builtin_amdgcn_mfma_f32_16x16x32_bf16(af[rt], bfr[c], acc[rt][c], 0, 0, 0);
    __syncthreads();
  }

  // epilogue: C/D layout col=lane&15, row=(lane>>4)*4+reg
#pragma unroll
  for (int rt = 0; rt < 2; ++rt)
#pragma unroll
    for (int ri = 0; ri < 4; ++ri) {
      int gr = gm0 + wave * 32 + rt * 16 + lq * 4 + ri;
      if (gr < M) {
#pragma unroll
        for (int c = 0; c < CT; ++c)
          Cb[(size_t)gr * BN + c * 16 + lr] = f2bf(acc[rt][c][ri]);
      }
    }

  // fused alpha dots: each 16-lane group (fixed lq) holds a full row
  float avs[CT], avd[CT];
#pragma unroll
  for (int c = 0; c < CT; ++c) {
    avs[c] = a_src[c * 16 + lr];
    avd[c] = a_dst[c * 16 + lr];
  }
#pragma unroll
  for (int rt = 0; rt < 2; ++rt)
#pragma unroll
    for (int ri = 0; ri < 4; ++ri) {
      int gr = gm0 + wave * 32 + rt * 16 + lq * 4 + ri;
      float s = 0.f, d = 0.f;
#pragma unroll
      for (int c = 0; c < CT; ++c) {
        float hv = acc[rt][c][ri];
        s += hv * avs[c];
        d += hv * avd[c];
      }
#pragma unroll
      for (int off = 1; off < 16; off <<= 1) {
        s += __shfl_xor(s, off);
        d += __shfl_xor(d, off);
      }
      if (gr < M && lr == 0) {
        as_[gr] = s;
        ad_[gr] = d;
      }
    }
}

// ------------------------------------------------------------ CSR build ----
__global__ void zero_kernel(int* __restrict__ p, int n) {
  int i = blockIdx.x * blockDim.x + threadIdx.x;
  if (i < n) p[i] = 0;
}

// append (src,dst) pairs into fixed-size bucket regions
__global__ void bucket_scatter(const int* __restrict__ src, const int* __restrict__ dst,
                               int* __restrict__ bcur, uint2* __restrict__ staged) {
  int i = blockIdx.x * blockDim.x + threadIdx.x;
  if (i >= N_EDGES) return;
  int s = src[i], d = dst[i];
  int b = d >> BSH;
  int p = atomicAdd(&bcur[b], 1);
  if (p < CAPS) staged[(size_t)b * CAPS + p] = make_uint2((uint)s, (uint)d);
}

// one block per bucket: LDS hist + scan + self-loops + local scatter
__global__ __launch_bounds__(256) void fine_kernel(
    const uint2* __restrict__ staged, const int* __restrict__ bcur,
    int* __restrict__ counts, int* __restrict__ offs, int* __restrict__ csr_src) {
  __shared__ int hist[128];
  __shared__ int cur[128];
  const int b = blockIdx.x, t = threadIdx.x;
  const int n0 = b << BSH;
  const int nn = min(128, N_NODES - n0);
  if (t < 128) hist[t] = 0;
  __syncthreads();
  const int ce = min(bcur[b], CAPS);
  const uint2* sp = staged + (size_t)b * CAPS;
  for (int i = t; i < ce; i += 256)
    atomicAdd(&hist[(int)sp[i].y - n0], 1);
  __syncthreads();
  // inclusive scan of (hist + selfloop) over 128 entries
  int v = 0;
  if (t < 128) {
    v = (t < nn) ? hist[t] + 1 : 0;
    cur[t] = v;
  }
  __syncthreads();
  for (int off = 1; off < 128; off <<= 1) {
    int x = 0;
    if (t < 128 && t >= off) x = cur[t - off];
    __syncthreads();
    if (t < 128) cur[t] += x;
    __syncthreads();
  }
  int excl = (t < 128) ? cur[t] - v : 0;
  __syncthreads();
  if (t < nn) {
    counts[n0 + t] = v;                   // includes self loop
    offs[n0 + t] = b * CAP + excl;
    csr_src[b * CAP + excl] = n0 + t;     // self loop placed first
    cur[t] = excl + 1;
  }
  __syncthreads();
  for (int i = t; i < ce; i += 256) {
    uint2 e = sp[i];
    int p = atomicAdd(&cur[(int)e.y - n0], 1);
    csr_src[b * CAP + p] = (int)e.x;
  }
}

// ------------------------------------------------------- GAT aggregation ----
// One wave per destination node; h is bf16 [M][C]. Online softmax (1 pass)
// then gather pass with x8 unroll for MLP.
template <int C, bool RELU, bool OUTBF>
__global__ __launch_bounds__(256) void agg_kernel(
    const ushort* __restrict__ h, const float* __restrict__ as_,
    const float* __restrict__ ad_, const int* __restrict__ offs,
    const int* __restrict__ counts, const int* __restrict__ csr_src,
    const float* __restrict__ bias, void* __restrict__ outp, int M) {
  int wid = (int)((blockIdx.x * (size_t)blockDim.x + threadIdx.x) >> 6);
  int lane = threadIdx.x & 63;
  if (wid >= M) return;
  const int start = offs[wid];
  const int cnt = counts[wid];
  const float adn = ad_[wid];

  // online max + denom
  float m = -3.402823e38f, ssum = 0.f;
  for (int j = lane; j < cnt; j += 64) {
    float e = as_[csr_src[start + j]] + adn;
    e = (e >= 0.f) ? e : NEG_SLOPE * e;
    float mn = fmaxf(m, e);
    ssum = ssum * __expf(m - mn) + __expf(e - mn);
    m = mn;
  }
#pragma unroll
  for (int off = 32; off; off >>= 1) {
    float mo = __shfl_xor(m, off), so = __shfl_xor(ssum, off);
    float mn = fmaxf(m, mo);
    ssum = ssum * __expf(m - mn) + so * __expf(mo - mn);
    m = mn;
  }
  const float inv = 1.0f / ssum;

  float acc0 = 0.f, acc1 = 0.f;
  for (int j0 = 0; j0 < cnt; j0 += 64) {
    int j = j0 + lane;
    int sj = 0;
    float pj = 0.f;
    if (j < cnt) {
      sj = csr_src[start + j];
      float e = as_[sj] + adn;
      e = (e >= 0.f) ? e : NEG_SLOPE * e;
      pj = __expf(e - m) * inv;
    }
    int c2 = min(64, cnt - j0);
    int jj = 0;
    for (; jj + 8 <= c2; jj += 8) {
      float pp[8];
      if (C == 128) {
        uint vv[8];
#pragma unroll
        for (int q = 0; q < 8; ++q) {
          int sq = __shfl(sj, jj + q);
          pp[q] = __shfl(pj, jj + q);
          vv[q] = ((const uint*)(h + (size_t)sq * C))[lane];
        }
#pragma unroll
        for (int q = 0; q < 8; ++q) {
          acc0 += pp[q] * bf2f((ushort)(vv[q] & 0xffffu));
          acc1 += pp[q] * bf2f((ushort)(vv[q] >> 16));
        }
      } else {
        ushort vv[8];
#pragma unroll
        for (int q = 0; q < 8; ++q) {
          int sq = __shfl(sj, jj + q);
          pp[q] = __shfl(pj, jj + q);
          vv[q] = h[(size_t)sq * C + lane];
        }
#pragma unroll
        for (int q = 0; q < 8; ++q) acc0 += pp[q] * bf2f(vv[q]);
      }
    }
    for (; jj < c2; ++jj) {
      int s0 = __shfl(sj, jj);
      float p0 = __shfl(pj, jj);
      if (C == 128) {
        uint v0 = ((const uint*)(h + (size_t)s0 * C))[lane];
        acc0 += p0 * bf2f((ushort)(v0 & 0xffffu));
        acc1 += p0 * bf2f((ushort)(v0 >> 16));
      } else {
        acc0 += p0 * bf2f(h[(size_t)s0 * C + lane]);
      }
    }
  }

  if (C == 128) {
    float r0 = acc0 + bias[2 * lane];
    float r1 = acc1 + bias[2 * lane + 1];
    if (RELU) {
      r0 = fmaxf(r0, 0.f);
      r1 = fmaxf(r1, 0.f);
    }
    if (OUTBF)
      ((uint*)outp)[(size_t)wid * (C / 2) + lane] = pack2(r0, r1);
    else
      ((float2*)outp)[(size_t)wid * (C / 2) + lane] = make_float2(r0, r1);
  } else {
    float r0 = acc0 + bias[lane];
    if (RELU) r0 = fmaxf(r0, 0.f);
    if (OUTBF)
      ((ushort*)outp)[(size_t)wid * C + lane] = f2bf(r0);
    else
      ((float*)outp)[(size_t)wid * C + lane] = r0;
  }
}

// ---------------------------------------------------------------- launch ----
extern "C" void kernel_launch(void* const* d_in, const int* in_sizes, int n_in,
                              void* d_out, int out_size, void* d_ws, size_t ws_size,
                              hipStream_t stream) {
  const float* x = (const float*)d_in[0];
  const int* ei = (const int*)d_in[1];
  const float* W1 = (const float*)d_in[2];
  const float* a1s = (const float*)d_in[3];
  const float* a1d = (const float*)d_in[4];
  const float* b1 = (const float*)d_in[5];
  const float* W2 = (const float*)d_in[6];
  const float* a2s = (const float*)d_in[7];
  const float* a2d = (const float*)d_in[8];
  const float* b2 = (const float*)d_in[9];
  float* out = (float*)d_out;

  const int* esrc = ei;
  const int* edst = ei + N_EDGES;

  char* ws = (char*)d_ws;
  size_t off = 0;
  auto alloc = [&](size_t bytes) {
    size_t o = off;
    off = (off + bytes + 255) & ~(size_t)255;
    return o;
  };
  ushort* h1b = (ushort*)(ws + alloc((size_t)N_NODES * F_HID * 2));
  ushort* hrb = (ushort*)(ws + alloc((size_t)N_NODES * F_HID * 2));
  ushort* h2b = (ushort*)(ws + alloc((size_t)N_NODES * F_OUT * 2));
  float* as1 = (float*)(ws + alloc((size_t)N_NODES * 4));
  float* ad1 = (float*)(ws + alloc((size_t)N_NODES * 4));
  float* as2 = (float*)(ws + alloc((size_t)N_NODES * 4));
  float* ad2 = (float*)(ws + alloc((size_t)N_NODES * 4));
  int* counts = (int*)(ws + alloc((size_t)N_NODES * 4));
  int* offs = (int*)(ws + alloc((size_t)N_NODES * 4));
  int* bcur = (int*)(ws + alloc((size_t)NB * 4));
  uint2* staged = (uint2*)(ws + alloc((size_t)NB * CAPS * 8));
  int* csr_src = (int*)(ws + alloc((size_t)NB * CAP * 4));
  ushort* W1t = (ushort*)(ws + alloc((size_t)F_IN * F_HID * 2));
  ushort* W2t = (ushort*)(ws + alloc((size_t)F_HID * F_OUT * 2));

  // CSR build (bucketed)
  zero_kernel<<<(NB + 255) / 256, 256, 0, stream>>>(bcur, NB);
  bucket_scatter<<<(N_EDGES + 255) / 256, 256, 0, stream>>>(esrc, edst, bcur, staged);
  fine_kernel<<<NB, 256, 0, stream>>>(staged, bcur, counts, offs, csr_src);

  // weight prep
  wprep_kernel<<<(F_IN * F_HID + 255) / 256, 256, 0, stream>>>(W1, W1t, F_IN, F_HID);
  wprep_kernel<<<(F_HID * F_OUT + 255) / 256, 256, 0, stream>>>(W2, W2t, F_HID, F_OUT);

  // layer 1
  gemm_mfma<F_HID, F_IN, true><<<(N_NODES + 127) / 128, 256, 0, stream>>>(
      x, W1t, h1b, a1s, a1d, as1, ad1, N_NODES);
  agg_kernel<F_HID, true, true><<<(N_NODES + 3) / 4, 256, 0, stream>>>(
      h1b, as1, ad1, offs, counts, csr_src, b1, hrb, N_NODES);

  // layer 2
  gemm_mfma<F_OUT, F_HID, false><<<(N_NODES + 127) / 128, 256, 0, stream>>>(
      hrb, W2t, h2b, a2s, a2d, as2, ad2, N_NODES);
  agg_kernel<F_OUT, false, false><<<(N_NODES + 3) / 4, 256, 0, stream>>>(
      h2b, as2, ad2, offs, counts, csr_src, b2, out, N_NODES);
}

// Round 5
// 421.839 us; speedup vs baseline: 1.7848x; 1.7848x over previous
//
#include <hip/hip_runtime.h>
#include <hip/hip_bf16.h>
#include <cstdint>

#define N_NODES 100000
#define N_EDGES 1600000
#define F_IN 256
#define F_HID 128
#define F_OUT 64
#define NEG_SLOPE 0.2f

// bucketed CSR build
#define BSH 7                      // 128 nodes per bucket
#define NB 782                     // ceil(100000/128)
#define CAP 3072                   // csr slots per bucket (edges+selfloops), mean 2304
#define CAPS 3072                  // staged slots per bucket (edges only), mean 2046
#define NBLK_E 256                 // edge-chunk blocks (== escan block size)

typedef __attribute__((ext_vector_type(8))) short bf16x8;
typedef __attribute__((ext_vector_type(4))) float f32x4;

__device__ __forceinline__ ushort f2bf(float f) {
  uint u = __float_as_uint(f);
  u += 0x7fffu + ((u >> 16) & 1u);   // RNE
  return (ushort)(u >> 16);
}
__device__ __forceinline__ float bf2f(ushort s) {
  return __uint_as_float(((uint)s) << 16);
}
__device__ __forceinline__ uint pack2(float a, float b) {
  return (uint)f2bf(a) | ((uint)f2bf(b) << 16);
}

// ------------------------------------------------- W prep: transpose + bf16
__global__ void wprep_kernel(const float* __restrict__ W, ushort* __restrict__ Wt,
                             int K, int Ncol) {
  int i = blockIdx.x * blockDim.x + threadIdx.x;
  if (i < K * Ncol) {
    int k = i / Ncol, c = i % Ncol;
    Wt[(size_t)c * K + k] = f2bf(W[i]);
  }
}

// ----------------------------------------------------------- MFMA GEMM ----
// C[M x BN] (bf16) = A[M x K] @ Bt^T, Bt is [BN][K] bf16. Block: 256 thr,
// BM=128, 4 waves each own 32 rows x BN cols. K-step 32, 16x16x32 mfma.
// Fused epilogue: as_[r] = h[r,:].a_src, ad_[r] = h[r,:].a_dst (f32 acc).
template <int BN, int K, bool AF32>
__global__ __launch_bounds__(256) void gemm_mfma(
    const void* __restrict__ Ap, const ushort* __restrict__ Bt,
    ushort* __restrict__ Cb, const float* __restrict__ a_src,
    const float* __restrict__ a_dst, float* __restrict__ as_,
    float* __restrict__ ad_, int M) {
  constexpr int CT = BN / 16;
  __shared__ __align__(16) ushort Alds[128 * 32];
  __shared__ __align__(16) ushort Blds[BN * 32];
  const int tid = threadIdx.x;
  const int wave = tid >> 6, lane = tid & 63;
  const int lr = lane & 15, lq = lane >> 4;
  const int gm0 = blockIdx.x * 128;

  f32x4 acc[2][CT];
#pragma unroll
  for (int a = 0; a < 2; ++a)
#pragma unroll
    for (int b = 0; b < CT; ++b)
#pragma unroll
      for (int e = 0; e < 4; ++e) acc[a][b][e] = 0.f;

  for (int kt = 0; kt < K; kt += 32) {
    // A stage: 512 segs of 16B (8 bf16), seg-XOR swizzled
#pragma unroll
    for (int i = 0; i < 2; ++i) {
      int sid = i * 256 + tid;
      int row = sid >> 2, q = sid & 3;
      int gm = gm0 + row;
      uint4 w = make_uint4(0u, 0u, 0u, 0u);
      if (gm < M) {
        if (AF32) {
          const float* s = (const float*)Ap + (size_t)gm * K + kt + q * 8;
          float4 u = *(const float4*)s;
          float4 v = *(const float4*)(s + 4);
          w.x = pack2(u.x, u.y); w.y = pack2(u.z, u.w);
          w.z = pack2(v.x, v.y); w.w = pack2(v.z, v.w);
        } else {
          w = *(const uint4*)((const ushort*)Ap + (size_t)gm * K + kt + q * 8);
        }
      }
      int phys = row * 4 + (q ^ ((row >> 2) & 3));
      *(uint4*)&Alds[phys * 8] = w;
    }
    // B stage
#pragma unroll
    for (int i = 0; i < BN * 4 / 256; ++i) {
      int sid = i * 256 + tid;
      int row = sid >> 2, q = sid & 3;
      uint4 w = *(const uint4*)(Bt + (size_t)row * K + kt + q * 8);
      int phys = row * 4 + (q ^ ((row >> 2) & 3));
      *(uint4*)&Blds[phys * 8] = w;
    }
    __syncthreads();

    bf16x8 af[2], bfr[CT];
#pragma unroll
    for (int rt = 0; rt < 2; ++rt) {
      int r = wave * 32 + rt * 16 + lr;
      af[rt] = *(const bf16x8*)&Alds[(r * 4 + (lq ^ ((r >> 2) & 3))) * 8];
    }
#pragma unroll
    for (int c = 0; c < CT; ++c) {
      int r = c * 16 + lr;
      bfr[c] = *(const bf16x8*)&Blds[(r * 4 + (lq ^ ((r >> 2) & 3))) * 8];
    }
#pragma unroll
    for (int rt = 0; rt < 2; ++rt)
#pragma unroll
      for (int c = 0; c < CT; ++c)
        acc[rt][c] = __builtin_amdgcn_mfma_f32_16x16x32_bf16(af[rt], bfr[c], acc[rt][c], 0, 0, 0);
    __syncthreads();
  }

  // epilogue: C/D layout col=lane&15, row=(lane>>4)*4+reg
#pragma unroll
  for (int rt = 0; rt < 2; ++rt)
#pragma unroll
    for (int ri = 0; ri < 4; ++ri) {
      int gr = gm0 + wave * 32 + rt * 16 + lq * 4 + ri;
      if (gr < M) {
#pragma unroll
        for (int c = 0; c < CT; ++c)
          Cb[(size_t)gr * BN + c * 16 + lr] = f2bf(acc[rt][c][ri]);
      }
    }

  // fused alpha dots: each 16-lane group (fixed lq) holds a full row
  float avs[CT], avd[CT];
#pragma unroll
  for (int c = 0; c < CT; ++c) {
    avs[c] = a_src[c * 16 + lr];
    avd[c] = a_dst[c * 16 + lr];
  }
#pragma unroll
  for (int rt = 0; rt < 2; ++rt)
#pragma unroll
    for (int ri = 0; ri < 4; ++ri) {
      int gr = gm0 + wave * 32 + rt * 16 + lq * 4 + ri;
      float s = 0.f, d = 0.f;
#pragma unroll
      for (int c = 0; c < CT; ++c) {
        float hv = acc[rt][c][ri];
        s += hv * avs[c];
        d += hv * avd[c];
      }
#pragma unroll
      for (int off = 1; off < 16; off <<= 1) {
        s += __shfl_xor(s, off);
        d += __shfl_xor(d, off);
      }
      if (gr < M && lr == 0) {
        as_[gr] = s;
        ad_[gr] = d;
      }
    }
}

// ------------------------------------------------------------ CSR build ----
// Deterministic two-level bucket build: per-block LDS hist -> global scan ->
// re-read + LDS-cursor scatter. ZERO global atomics (round-4's 378us lesson:
// 782 shared cursors x ~2046 atomics/address serialized at ~185ns each).

// A: per-block histogram over buckets
__global__ __launch_bounds__(256) void ehist_kernel(const int* __restrict__ dst,
                                                    int* __restrict__ hist_blk) {
  __shared__ int h[NB];
  for (int t = threadIdx.x; t < NB; t += 256) h[t] = 0;
  __syncthreads();
  const int per = (N_EDGES + NBLK_E - 1) / NBLK_E;
  const int e0 = blockIdx.x * per;
  const int e1 = min(e0 + per, N_EDGES);
  for (int i = e0 + threadIdx.x; i < e1; i += 256)
    atomicAdd(&h[dst[i] >> BSH], 1);
  __syncthreads();
  for (int t = threadIdx.x; t < NB; t += 256)
    hist_blk[blockIdx.x * NB + t] = h[t];
}

// B: per bucket, exclusive scan over the NBLK_E block counts
__global__ __launch_bounds__(NBLK_E) void escan_kernel(int* __restrict__ hist_blk,
                                                       int* __restrict__ btotal) {
  __shared__ int sh[NBLK_E];
  const int j = blockIdx.x, t = threadIdx.x;
  int v = hist_blk[t * NB + j];
  sh[t] = v;
  __syncthreads();
  for (int off = 1; off < NBLK_E; off <<= 1) {
    int x = (t >= off) ? sh[t - off] : 0;
    __syncthreads();
    sh[t] += x;
    __syncthreads();
  }
  hist_blk[t * NB + j] = sh[t] - v;  // exclusive base for (block t, bucket j)
  if (t == NBLK_E - 1) btotal[j] = sh[NBLK_E - 1];
}

// C: scatter edges into bucket regions, packed (src<<7)|local
__global__ __launch_bounds__(256) void escatter_kernel(
    const int* __restrict__ src, const int* __restrict__ dst,
    const int* __restrict__ hist_blk, uint* __restrict__ staged) {
  __shared__ int cur[NB];
  for (int t = threadIdx.x; t < NB; t += 256)
    cur[t] = hist_blk[blockIdx.x * NB + t];
  __syncthreads();
  const int per = (N_EDGES + NBLK_E - 1) / NBLK_E;
  const int e0 = blockIdx.x * per;
  const int e1 = min(e0 + per, N_EDGES);
  for (int i = e0 + threadIdx.x; i < e1; i += 256) {
    int d = dst[i];
    int b = d >> BSH;
    int p = atomicAdd(&cur[b], 1);
    if (p < CAPS)
      staged[(size_t)b * CAPS + p] = ((uint)src[i] << BSH) | (uint)(d & ((1 << BSH) - 1));
  }
}

// one block per bucket: LDS hist + scan + self-loops + local scatter
__global__ __launch_bounds__(256) void fine_kernel(
    const uint* __restrict__ staged, const int* __restrict__ btotal,
    int* __restrict__ counts, int* __restrict__ offs, int* __restrict__ csr_src) {
  __shared__ int hist[128];
  __shared__ int cur[128];
  const int b = blockIdx.x, t = threadIdx.x;
  const int n0 = b << BSH;
  const int nn = min(128, N_NODES - n0);
  if (t < 128) hist[t] = 0;
  __syncthreads();
  const int ce = min(btotal[b], CAPS);
  const uint* sp = staged + (size_t)b * CAPS;
  for (int i = t; i < ce; i += 256)
    atomicAdd(&hist[sp[i] & 127], 1);
  __syncthreads();
  // inclusive scan of (hist + selfloop) over 128 entries
  int v = 0;
  if (t < 128) {
    v = (t < nn) ? hist[t] + 1 : 0;
    cur[t] = v;
  }
  __syncthreads();
  for (int off = 1; off < 128; off <<= 1) {
    int x = 0;
    if (t < 128 && t >= off) x = cur[t - off];
    __syncthreads();
    if (t < 128) cur[t] += x;
    __syncthreads();
  }
  int excl = (t < 128) ? cur[t] - v : 0;
  __syncthreads();
  if (t < nn) {
    counts[n0 + t] = v;                   // includes self loop
    offs[n0 + t] = b * CAP + excl;
    csr_src[b * CAP + excl] = n0 + t;     // self loop placed first
    cur[t] = excl + 1;
  }
  __syncthreads();
  for (int i = t; i < ce; i += 256) {
    uint e = sp[i];
    int p = atomicAdd(&cur[e & 127], 1);
    csr_src[b * CAP + p] = (int)(e >> BSH);
  }
}

// ------------------------------------------------------- GAT aggregation ----
// One wave per destination node; h is bf16 [M][C]. Online softmax (1 pass)
// then gather pass with x8 unroll for MLP.
template <int C, bool RELU, bool OUTBF>
__global__ __launch_bounds__(256) void agg_kernel(
    const ushort* __restrict__ h, const float* __restrict__ as_,
    const float* __restrict__ ad_, const int* __restrict__ offs,
    const int* __restrict__ counts, const int* __restrict__ csr_src,
    const float* __restrict__ bias, void* __restrict__ outp, int M) {
  int wid = (int)((blockIdx.x * (size_t)blockDim.x + threadIdx.x) >> 6);
  int lane = threadIdx.x & 63;
  if (wid >= M) return;
  const int start = offs[wid];
  const int cnt = counts[wid];
  const float adn = ad_[wid];

  // online max + denom
  float m = -3.402823e38f, ssum = 0.f;
  for (int j = lane; j < cnt; j += 64) {
    float e = as_[csr_src[start + j]] + adn;
    e = (e >= 0.f) ? e : NEG_SLOPE * e;
    float mn = fmaxf(m, e);
    ssum = ssum * __expf(m - mn) + __expf(e - mn);
    m = mn;
  }
#pragma unroll
  for (int off = 32; off; off >>= 1) {
    float mo = __shfl_xor(m, off), so = __shfl_xor(ssum, off);
    float mn = fmaxf(m, mo);
    ssum = ssum * __expf(m - mn) + so * __expf(mo - mn);
    m = mn;
  }
  const float inv = 1.0f / ssum;

  float acc0 = 0.f, acc1 = 0.f;
  for (int j0 = 0; j0 < cnt; j0 += 64) {
    int j = j0 + lane;
    int sj = 0;
    float pj = 0.f;
    if (j < cnt) {
      sj = csr_src[start + j];
      float e = as_[sj] + adn;
      e = (e >= 0.f) ? e : NEG_SLOPE * e;
      pj = __expf(e - m) * inv;
    }
    int c2 = min(64, cnt - j0);
    int jj = 0;
    for (; jj + 8 <= c2; jj += 8) {
      float pp[8];
      if (C == 128) {
        uint vv[8];
#pragma unroll
        for (int q = 0; q < 8; ++q) {
          int sq = __shfl(sj, jj + q);
          pp[q] = __shfl(pj, jj + q);
          vv[q] = ((const uint*)(h + (size_t)sq * C))[lane];
        }
#pragma unroll
        for (int q = 0; q < 8; ++q) {
          acc0 += pp[q] * bf2f((ushort)(vv[q] & 0xffffu));
          acc1 += pp[q] * bf2f((ushort)(vv[q] >> 16));
        }
      } else {
        ushort vv[8];
#pragma unroll
        for (int q = 0; q < 8; ++q) {
          int sq = __shfl(sj, jj + q);
          pp[q] = __shfl(pj, jj + q);
          vv[q] = h[(size_t)sq * C + lane];
        }
#pragma unroll
        for (int q = 0; q < 8; ++q) acc0 += pp[q] * bf2f(vv[q]);
      }
    }
    for (; jj < c2; ++jj) {
      int s0 = __shfl(sj, jj);
      float p0 = __shfl(pj, jj);
      if (C == 128) {
        uint v0 = ((const uint*)(h + (size_t)s0 * C))[lane];
        acc0 += p0 * bf2f((ushort)(v0 & 0xffffu));
        acc1 += p0 * bf2f((ushort)(v0 >> 16));
      } else {
        acc0 += p0 * bf2f(h[(size_t)s0 * C + lane]);
      }
    }
  }

  if (C == 128) {
    float r0 = acc0 + bias[2 * lane];
    float r1 = acc1 + bias[2 * lane + 1];
    if (RELU) {
      r0 = fmaxf(r0, 0.f);
      r1 = fmaxf(r1, 0.f);
    }
    if (OUTBF)
      ((uint*)outp)[(size_t)wid * (C / 2) + lane] = pack2(r0, r1);
    else
      ((float2*)outp)[(size_t)wid * (C / 2) + lane] = make_float2(r0, r1);
  } else {
    float r0 = acc0 + bias[lane];
    if (RELU) r0 = fmaxf(r0, 0.f);
    if (OUTBF)
      ((ushort*)outp)[(size_t)wid * C + lane] = f2bf(r0);
    else
      ((float*)outp)[(size_t)wid * C + lane] = r0;
  }
}

// ---------------------------------------------------------------- launch ----
extern "C" void kernel_launch(void* const* d_in, const int* in_sizes, int n_in,
                              void* d_out, int out_size, void* d_ws, size_t ws_size,
                              hipStream_t stream) {
  const float* x = (const float*)d_in[0];
  const int* ei = (const int*)d_in[1];
  const float* W1 = (const float*)d_in[2];
  const float* a1s = (const float*)d_in[3];
  const float* a1d = (const float*)d_in[4];
  const float* b1 = (const float*)d_in[5];
  const float* W2 = (const float*)d_in[6];
  const float* a2s = (const float*)d_in[7];
  const float* a2d = (const float*)d_in[8];
  const float* b2 = (const float*)d_in[9];
  float* out = (float*)d_out;

  const int* esrc = ei;
  const int* edst = ei + N_EDGES;

  char* ws = (char*)d_ws;
  size_t off = 0;
  auto alloc = [&](size_t bytes) {
    size_t o = off;
    off = (off + bytes + 255) & ~(size_t)255;
    return o;
  };
  ushort* h1b = (ushort*)(ws + alloc((size_t)N_NODES * F_HID * 2));
  ushort* hrb = (ushort*)(ws + alloc((size_t)N_NODES * F_HID * 2));
  ushort* h2b = (ushort*)(ws + alloc((size_t)N_NODES * F_OUT * 2));
  float* as1 = (float*)(ws + alloc((size_t)N_NODES * 4));
  float* ad1 = (float*)(ws + alloc((size_t)N_NODES * 4));
  float* as2 = (float*)(ws + alloc((size_t)N_NODES * 4));
  float* ad2 = (float*)(ws + alloc((size_t)N_NODES * 4));
  int* counts = (int*)(ws + alloc((size_t)N_NODES * 4));
  int* offs = (int*)(ws + alloc((size_t)N_NODES * 4));
  int* hist_blk = (int*)(ws + alloc((size_t)NBLK_E * NB * 4));
  int* btotal = (int*)(ws + alloc((size_t)NB * 4));
  uint* staged = (uint*)(ws + alloc((size_t)NB * CAPS * 4));
  int* csr_src = (int*)(ws + alloc((size_t)NB * CAP * 4));
  ushort* W1t = (ushort*)(ws + alloc((size_t)F_IN * F_HID * 2));
  ushort* W2t = (ushort*)(ws + alloc((size_t)F_HID * F_OUT * 2));

  // CSR build (deterministic bucketed, no global atomics)
  ehist_kernel<<<NBLK_E, 256, 0, stream>>>(edst, hist_blk);
  escan_kernel<<<NB, NBLK_E, 0, stream>>>(hist_blk, btotal);
  escatter_kernel<<<NBLK_E, 256, 0, stream>>>(esrc, edst, hist_blk, staged);
  fine_kernel<<<NB, 256, 0, stream>>>(staged, btotal, counts, offs, csr_src);

  // weight prep
  wprep_kernel<<<(F_IN * F_HID + 255) / 256, 256, 0, stream>>>(W1, W1t, F_IN, F_HID);
  wprep_kernel<<<(F_HID * F_OUT + 255) / 256, 256, 0, stream>>>(W2, W2t, F_HID, F_OUT);

  // layer 1
  gemm_mfma<F_HID, F_IN, true><<<(N_NODES + 127) / 128, 256, 0, stream>>>(
      x, W1t, h1b, a1s, a1d, as1, ad1, N_NODES);
  agg_kernel<F_HID, true, true><<<(N_NODES + 3) / 4, 256, 0, stream>>>(
      h1b, as1, ad1, offs, counts, csr_src, b1, hrb, N_NODES);

  // layer 2
  gemm_mfma<F_OUT, F_HID, false><<<(N_NODES + 127) / 128, 256, 0, stream>>>(
      hrb, W2t, h2b, a2s, a2d, as2, ad2, N_NODES);
  agg_kernel<F_OUT, false, false><<<(N_NODES + 3) / 4, 256, 0, stream>>>(
      h2b, as2, ad2, offs, counts, csr_src, b2, out, N_NODES);
}

// Round 6
// 401.592 us; speedup vs baseline: 1.8747x; 1.0504x over previous
//
#include <hip/hip_runtime.h>
#include <hip/hip_bf16.h>
#include <cstdint>

#define N_NODES 100000
#define N_EDGES 1600000
#define F_IN 256
#define F_HID 128
#define F_OUT 64
#define NEG_SLOPE 0.2f

// bucketed CSR build
#define BSH 7                      // 128 nodes per bucket
#define NB 782                     // ceil(100000/128)
#define CAP 3072                   // csr slots per bucket (edges+selfloops)
#define CAPS 3072                  // staged slots per bucket (edges only)
#define NBLK_E 256                 // edge-chunk blocks (== escan block size)

typedef __attribute__((ext_vector_type(8))) short bf16x8;
typedef __attribute__((ext_vector_type(4))) float f32x4;

__device__ __forceinline__ ushort f2bf(float f) {
  uint u = __float_as_uint(f);
  u += 0x7fffu + ((u >> 16) & 1u);   // RNE
  return (ushort)(u >> 16);
}
__device__ __forceinline__ float bf2f(ushort s) {
  return __uint_as_float(((uint)s) << 16);
}
__device__ __forceinline__ uint pack2(float a, float b) {
  return (uint)f2bf(a) | ((uint)f2bf(b) << 16);
}

// ------------------------------------------------- W prep: transpose + bf16
__global__ void wprep_kernel(const float* __restrict__ W, ushort* __restrict__ Wt,
                             int K, int Ncol) {
  int i = blockIdx.x * blockDim.x + threadIdx.x;
  if (i < K * Ncol) {
    int k = i / Ncol, c = i % Ncol;
    Wt[(size_t)c * K + k] = f2bf(W[i]);
  }
}

// ----------------------------------------------------------- MFMA GEMM ----
template <int BN, int K, bool AF32>
__global__ __launch_bounds__(256) void gemm_mfma(
    const void* __restrict__ Ap, const ushort* __restrict__ Bt,
    ushort* __restrict__ Cb, const float* __restrict__ a_src,
    const float* __restrict__ a_dst, float* __restrict__ as_,
    float* __restrict__ ad_, int M) {
  constexpr int CT = BN / 16;
  __shared__ __align__(16) ushort Alds[128 * 32];
  __shared__ __align__(16) ushort Blds[BN * 32];
  const int tid = threadIdx.x;
  const int wave = tid >> 6, lane = tid & 63;
  const int lr = lane & 15, lq = lane >> 4;
  const int gm0 = blockIdx.x * 128;

  f32x4 acc[2][CT];
#pragma unroll
  for (int a = 0; a < 2; ++a)
#pragma unroll
    for (int b = 0; b < CT; ++b)
#pragma unroll
      for (int e = 0; e < 4; ++e) acc[a][b][e] = 0.f;

  for (int kt = 0; kt < K; kt += 32) {
#pragma unroll
    for (int i = 0; i < 2; ++i) {
      int sid = i * 256 + tid;
      int row = sid >> 2, q = sid & 3;
      int gm = gm0 + row;
      uint4 w = make_uint4(0u, 0u, 0u, 0u);
      if (gm < M) {
        if (AF32) {
          const float* s = (const float*)Ap + (size_t)gm * K + kt + q * 8;
          float4 u = *(const float4*)s;
          float4 v = *(const float4*)(s + 4);
          w.x = pack2(u.x, u.y); w.y = pack2(u.z, u.w);
          w.z = pack2(v.x, v.y); w.w = pack2(v.z, v.w);
        } else {
          w = *(const uint4*)((const ushort*)Ap + (size_t)gm * K + kt + q * 8);
        }
      }
      int phys = row * 4 + (q ^ ((row >> 2) & 3));
      *(uint4*)&Alds[phys * 8] = w;
    }
#pragma unroll
    for (int i = 0; i < BN * 4 / 256; ++i) {
      int sid = i * 256 + tid;
      int row = sid >> 2, q = sid & 3;
      uint4 w = *(const uint4*)(Bt + (size_t)row * K + kt + q * 8);
      int phys = row * 4 + (q ^ ((row >> 2) & 3));
      *(uint4*)&Blds[phys * 8] = w;
    }
    __syncthreads();

    bf16x8 af[2], bfr[CT];
#pragma unroll
    for (int rt = 0; rt < 2; ++rt) {
      int r = wave * 32 + rt * 16 + lr;
      af[rt] = *(const bf16x8*)&Alds[(r * 4 + (lq ^ ((r >> 2) & 3))) * 8];
    }
#pragma unroll
    for (int c = 0; c < CT; ++c) {
      int r = c * 16 + lr;
      bfr[c] = *(const bf16x8*)&Blds[(r * 4 + (lq ^ ((r >> 2) & 3))) * 8];
    }
#pragma unroll
    for (int rt = 0; rt < 2; ++rt)
#pragma unroll
      for (int c = 0; c < CT; ++c)
        acc[rt][c] = __builtin_amdgcn_mfma_f32_16x16x32_bf16(af[rt], bfr[c], acc[rt][c], 0, 0, 0);
    __syncthreads();
  }

#pragma unroll
  for (int rt = 0; rt < 2; ++rt)
#pragma unroll
    for (int ri = 0; ri < 4; ++ri) {
      int gr = gm0 + wave * 32 + rt * 16 + lq * 4 + ri;
      if (gr < M) {
#pragma unroll
        for (int c = 0; c < CT; ++c)
          Cb[(size_t)gr * BN + c * 16 + lr] = f2bf(acc[rt][c][ri]);
      }
    }

  // fused alpha dots
  float avs[CT], avd[CT];
#pragma unroll
  for (int c = 0; c < CT; ++c) {
    avs[c] = a_src[c * 16 + lr];
    avd[c] = a_dst[c * 16 + lr];
  }
#pragma unroll
  for (int rt = 0; rt < 2; ++rt)
#pragma unroll
    for (int ri = 0; ri < 4; ++ri) {
      int gr = gm0 + wave * 32 + rt * 16 + lq * 4 + ri;
      float s = 0.f, d = 0.f;
#pragma unroll
      for (int c = 0; c < CT; ++c) {
        float hv = acc[rt][c][ri];
        s += hv * avs[c];
        d += hv * avd[c];
      }
#pragma unroll
      for (int off = 1; off < 16; off <<= 1) {
        s += __shfl_xor(s, off);
        d += __shfl_xor(d, off);
      }
      if (gr < M && lr == 0) {
        as_[gr] = s;
        ad_[gr] = d;
      }
    }
}

// ------------------------------------------------------------ CSR build ----
__global__ __launch_bounds__(256) void ehist_kernel(const int* __restrict__ dst,
                                                    int* __restrict__ hist_blk) {
  __shared__ int h[NB];
  for (int t = threadIdx.x; t < NB; t += 256) h[t] = 0;
  __syncthreads();
  const int per = (N_EDGES + NBLK_E - 1) / NBLK_E;
  const int e0 = blockIdx.x * per;
  const int e1 = min(e0 + per, N_EDGES);
  for (int i = e0 + threadIdx.x; i < e1; i += 256)
    atomicAdd(&h[dst[i] >> BSH], 1);
  __syncthreads();
  for (int t = threadIdx.x; t < NB; t += 256)
    hist_blk[blockIdx.x * NB + t] = h[t];
}

__global__ __launch_bounds__(NBLK_E) void escan_kernel(int* __restrict__ hist_blk,
                                                       int* __restrict__ btotal) {
  __shared__ int sh[NBLK_E];
  const int j = blockIdx.x, t = threadIdx.x;
  int v = hist_blk[t * NB + j];
  sh[t] = v;
  __syncthreads();
  for (int off = 1; off < NBLK_E; off <<= 1) {
    int x = (t >= off) ? sh[t - off] : 0;
    __syncthreads();
    sh[t] += x;
    __syncthreads();
  }
  hist_blk[t * NB + j] = sh[t] - v;
  if (t == NBLK_E - 1) btotal[j] = sh[NBLK_E - 1];
}

__global__ __launch_bounds__(256) void escatter_kernel(
    const int* __restrict__ src, const int* __restrict__ dst,
    const int* __restrict__ hist_blk, uint* __restrict__ staged) {
  __shared__ int cur[NB];
  for (int t = threadIdx.x; t < NB; t += 256)
    cur[t] = hist_blk[blockIdx.x * NB + t];
  __syncthreads();
  const int per = (N_EDGES + NBLK_E - 1) / NBLK_E;
  const int e0 = blockIdx.x * per;
  const int e1 = min(e0 + per, N_EDGES);
  for (int i = e0 + threadIdx.x; i < e1; i += 256) {
    int d = dst[i];
    int b = d >> BSH;
    int p = atomicAdd(&cur[b], 1);
    if (p < CAPS)
      staged[(size_t)b * CAPS + p] = ((uint)src[i] << BSH) | (uint)(d & ((1 << BSH) - 1));
  }
}

__global__ __launch_bounds__(256) void fine_kernel(
    const uint* __restrict__ staged, const int* __restrict__ btotal,
    int* __restrict__ counts, int* __restrict__ offs, int* __restrict__ csr_src) {
  __shared__ int hist[128];
  __shared__ int cur[128];
  const int b = blockIdx.x, t = threadIdx.x;
  const int n0 = b << BSH;
  const int nn = min(128, N_NODES - n0);
  if (t < 128) hist[t] = 0;
  __syncthreads();
  const int ce = min(btotal[b], CAPS);
  const uint* sp = staged + (size_t)b * CAPS;
  for (int i = t; i < ce; i += 256)
    atomicAdd(&hist[sp[i] & 127], 1);
  __syncthreads();
  int v = 0;
  if (t < 128) {
    v = (t < nn) ? hist[t] + 1 : 0;
    cur[t] = v;
  }
  __syncthreads();
  for (int off = 1; off < 128; off <<= 1) {
    int x = 0;
    if (t < 128 && t >= off) x = cur[t - off];
    __syncthreads();
    if (t < 128) cur[t] += x;
    __syncthreads();
  }
  int excl = (t < 128) ? cur[t] - v : 0;
  __syncthreads();
  if (t < nn) {
    counts[n0 + t] = v;
    offs[n0 + t] = b * CAP + excl;
    csr_src[b * CAP + excl] = n0 + t;     // self loop first
    cur[t] = excl + 1;
  }
  __syncthreads();
  for (int i = t; i < ce; i += 256) {
    uint e = sp[i];
    int p = atomicAdd(&cur[e & 127], 1);
    csr_src[b * CAP + p] = (int)(e >> BSH);
  }
}

// ------------------------------------------------------- GAT aggregation ----
// One wave per destination node; h is bf16 [M][C]. Online softmax, then
// latency-optimized gather:
//   C=128: readlane->SGPR broadcast (scalar base, SALU addressing), 16 loads
//          in flight; first chunk reuses pass-1 registers (no reload chain).
//   C=64 : half-wave 2-edges-per-load (256B/inst), 8 pairs in flight.
template <int C, bool RELU, bool OUTBF>
__global__ __launch_bounds__(256) void agg_kernel(
    const ushort* __restrict__ h, const float* __restrict__ as_,
    const float* __restrict__ ad_, const int* __restrict__ offs,
    const int* __restrict__ counts, const int* __restrict__ csr_src,
    const float* __restrict__ bias, void* __restrict__ outp, int M) {
  int wid = (int)((blockIdx.x * (size_t)blockDim.x + threadIdx.x) >> 6);
  int lane = threadIdx.x & 63;
  if (wid >= M) return;
  const int start = offs[wid];
  const int cnt = counts[wid];
  const float adn = ad_[wid];

  // pass 1: online max + denom; keep first-chunk (sj,e) in registers
  float m = -3.402823e38f, ssum = 0.f;
  int sj0 = 0;
  float e0 = -3.402823e38f;
  for (int j = lane; j < cnt; j += 64) {
    int sj = csr_src[start + j];
    float e = as_[sj] + adn;
    e = (e >= 0.f) ? e : NEG_SLOPE * e;
    if (j < 64) { sj0 = sj; e0 = e; }
    float mn = fmaxf(m, e);
    ssum = ssum * __expf(m - mn) + __expf(e - mn);
    m = mn;
  }
#pragma unroll
  for (int off = 32; off; off >>= 1) {
    float mo = __shfl_xor(m, off), so = __shfl_xor(ssum, off);
    float mn = fmaxf(m, mo);
    ssum = ssum * __expf(m - mn) + so * __expf(mo - mn);
    m = mn;
  }
  const float inv = 1.0f / ssum;

  float2 acc = make_float2(0.f, 0.f);
  const int half = lane >> 5;   // C==64 scheme
  const int cl = lane & 31;

  for (int j0 = 0; j0 < cnt; j0 += 64) {
    int j = j0 + lane;
    int sj;
    float pj;
    if (j0 == 0) {
      sj = sj0;
      pj = __expf(e0 - m) * inv;   // e0=-3.4e38 for idle lanes -> pj=0
    } else {
      sj = 0;
      pj = 0.f;
      if (j < cnt) {
        sj = csr_src[start + j];
        float e = as_[sj] + adn;
        e = (e >= 0.f) ? e : NEG_SLOPE * e;
        pj = __expf(e - m) * inv;
      }
    }
    int c2 = min(64, cnt - j0);
    int jj = 0;
    if (C == 128) {
      for (; jj + 16 <= c2; jj += 16) {
        uint vv[16];
        float pp[16];
#pragma unroll
        for (int q = 0; q < 16; ++q) {
          int sq = __builtin_amdgcn_readlane(sj, jj + q);
          pp[q] = __uint_as_float((uint)__builtin_amdgcn_readlane((int)__float_as_uint(pj), jj + q));
          vv[q] = *((const uint*)(h + (size_t)sq * C) + lane);
        }
#pragma unroll
        for (int q = 0; q < 16; ++q) {
          acc.x = fmaf(pp[q], bf2f((ushort)(vv[q] & 0xffffu)), acc.x);
          acc.y = fmaf(pp[q], bf2f((ushort)(vv[q] >> 16)), acc.y);
        }
      }
      for (; jj + 4 <= c2; jj += 4) {
        uint vv[4];
        float pp[4];
#pragma unroll
        for (int q = 0; q < 4; ++q) {
          int sq = __builtin_amdgcn_readlane(sj, jj + q);
          pp[q] = __uint_as_float((uint)__builtin_amdgcn_readlane((int)__float_as_uint(pj), jj + q));
          vv[q] = *((const uint*)(h + (size_t)sq * C) + lane);
        }
#pragma unroll
        for (int q = 0; q < 4; ++q) {
          acc.x = fmaf(pp[q], bf2f((ushort)(vv[q] & 0xffffu)), acc.x);
          acc.y = fmaf(pp[q], bf2f((ushort)(vv[q] >> 16)), acc.y);
        }
      }
      for (; jj < c2; ++jj) {
        int sq = __builtin_amdgcn_readlane(sj, jj);
        float pq = __uint_as_float((uint)__builtin_amdgcn_readlane((int)__float_as_uint(pj), jj));
        uint v = *((const uint*)(h + (size_t)sq * C) + lane);
        acc.x = fmaf(pq, bf2f((ushort)(v & 0xffffu)), acc.x);
        acc.y = fmaf(pq, bf2f((ushort)(v >> 16)), acc.y);
      }
    } else {
      // C == 64: half-wave handles alternating edges, 32 uints cover a row
      const uint* h32 = (const uint*)h;
      for (; jj + 16 <= c2; jj += 16) {
        uint vv[8];
        float pp[8];
#pragma unroll
        for (int q = 0; q < 8; ++q) {
          int idx = jj + 2 * q + half;
          int sq = __shfl(sj, idx);
          pp[q] = __shfl(pj, idx);
          vv[q] = h32[(size_t)sq * (C / 2) + cl];
        }
#pragma unroll
        for (int q = 0; q < 8; ++q) {
          acc.x = fmaf(pp[q], bf2f((ushort)(vv[q] & 0xffffu)), acc.x);
          acc.y = fmaf(pp[q], bf2f((ushort)(vv[q] >> 16)), acc.y);
        }
      }
      for (; jj < c2; jj += 2) {
        int idx = jj + half;
        int idc = min(idx, c2 - 1);
        int sq = __shfl(sj, idc);
        float pq = __shfl(pj, idc);
        if (idx >= c2) pq = 0.f;
        uint v = h32[(size_t)sq * (C / 2) + cl];
        acc.x = fmaf(pq, bf2f((ushort)(v & 0xffffu)), acc.x);
        acc.y = fmaf(pq, bf2f((ushort)(v >> 16)), acc.y);
      }
    }
  }

  if (C == 128) {
    float r0 = acc.x + bias[2 * lane];
    float r1 = acc.y + bias[2 * lane + 1];
    if (RELU) {
      r0 = fmaxf(r0, 0.f);
      r1 = fmaxf(r1, 0.f);
    }
    if (OUTBF)
      ((uint*)outp)[(size_t)wid * (C / 2) + lane] = pack2(r0, r1);
    else
      ((float2*)outp)[(size_t)wid * (C / 2) + lane] = make_float2(r0, r1);
  } else {
    // combine the two half-wave partial sums
    acc.x += __shfl_xor(acc.x, 32);
    acc.y += __shfl_xor(acc.y, 32);
    if (lane < 32) {
      float r0 = acc.x + bias[2 * cl];
      float r1 = acc.y + bias[2 * cl + 1];
      if (RELU) {
        r0 = fmaxf(r0, 0.f);
        r1 = fmaxf(r1, 0.f);
      }
      if (OUTBF)
        ((uint*)outp)[(size_t)wid * (C / 2) + cl] = pack2(r0, r1);
      else
        ((float2*)outp)[(size_t)wid * (C / 2) + cl] = make_float2(r0, r1);
    }
  }
}

// ---------------------------------------------------------------- launch ----
extern "C" void kernel_launch(void* const* d_in, const int* in_sizes, int n_in,
                              void* d_out, int out_size, void* d_ws, size_t ws_size,
                              hipStream_t stream) {
  const float* x = (const float*)d_in[0];
  const int* ei = (const int*)d_in[1];
  const float* W1 = (const float*)d_in[2];
  const float* a1s = (const float*)d_in[3];
  const float* a1d = (const float*)d_in[4];
  const float* b1 = (const float*)d_in[5];
  const float* W2 = (const float*)d_in[6];
  const float* a2s = (const float*)d_in[7];
  const float* a2d = (const float*)d_in[8];
  const float* b2 = (const float*)d_in[9];
  float* out = (float*)d_out;

  const int* esrc = ei;
  const int* edst = ei + N_EDGES;

  char* ws = (char*)d_ws;
  size_t off = 0;
  auto alloc = [&](size_t bytes) {
    size_t o = off;
    off = (off + bytes + 255) & ~(size_t)255;
    return o;
  };
  ushort* h1b = (ushort*)(ws + alloc((size_t)N_NODES * F_HID * 2));
  ushort* hrb = (ushort*)(ws + alloc((size_t)N_NODES * F_HID * 2));
  ushort* h2b = (ushort*)(ws + alloc((size_t)N_NODES * F_OUT * 2));
  float* as1 = (float*)(ws + alloc((size_t)N_NODES * 4));
  float* ad1 = (float*)(ws + alloc((size_t)N_NODES * 4));
  float* as2 = (float*)(ws + alloc((size_t)N_NODES * 4));
  float* ad2 = (float*)(ws + alloc((size_t)N_NODES * 4));
  int* counts = (int*)(ws + alloc((size_t)N_NODES * 4));
  int* offs = (int*)(ws + alloc((size_t)N_NODES * 4));
  int* hist_blk = (int*)(ws + alloc((size_t)NBLK_E * NB * 4));
  int* btotal = (int*)(ws + alloc((size_t)NB * 4));
  uint* staged = (uint*)(ws + alloc((size_t)NB * CAPS * 4));
  int* csr_src = (int*)(ws + alloc((size_t)NB * CAP * 4));
  ushort* W1t = (ushort*)(ws + alloc((size_t)F_IN * F_HID * 2));
  ushort* W2t = (ushort*)(ws + alloc((size_t)F_HID * F_OUT * 2));

  // CSR build (deterministic bucketed, no global atomics)
  ehist_kernel<<<NBLK_E, 256, 0, stream>>>(edst, hist_blk);
  escan_kernel<<<NB, NBLK_E, 0, stream>>>(hist_blk, btotal);
  escatter_kernel<<<NBLK_E, 256, 0, stream>>>(esrc, edst, hist_blk, staged);
  fine_kernel<<<NB, 256, 0, stream>>>(staged, btotal, counts, offs, csr_src);

  // weight prep
  wprep_kernel<<<(F_IN * F_HID + 255) / 256, 256, 0, stream>>>(W1, W1t, F_IN, F_HID);
  wprep_kernel<<<(F_HID * F_OUT + 255) / 256, 256, 0, stream>>>(W2, W2t, F_HID, F_OUT);

  // layer 1
  gemm_mfma<F_HID, F_IN, true><<<(N_NODES + 127) / 128, 256, 0, stream>>>(
      x, W1t, h1b, a1s, a1d, as1, ad1, N_NODES);
  agg_kernel<F_HID, true, true><<<(N_NODES + 3) / 4, 256, 0, stream>>>(
      h1b, as1, ad1, offs, counts, csr_src, b1, hrb, N_NODES);

  // layer 2
  gemm_mfma<F_OUT, F_HID, false><<<(N_NODES + 127) / 128, 256, 0, stream>>>(
      hrb, W2t, h2b, a2s, a2d, as2, ad2, N_NODES);
  agg_kernel<F_OUT, false, false><<<(N_NODES + 3) / 4, 256, 0, stream>>>(
      h2b, as2, ad2, offs, counts, csr_src, b2, out, N_NODES);
}